// Round 8
// baseline (530.853 us; speedup 1.0000x reference)
//
#include <hip/hip_runtime.h>
#include <hip/hip_bf16.h>
#include <hip/hip_fp16.h>
#include <stdint.h>

#define N_NODES 100000
#define N_EDGES 1600000
#define ET (N_EDGES + N_NODES)   // edges + self-loops
#define HID 128
#define C2 40
#define F2 80
#define NEG 0.2f
#define BN_EPS 1e-5f
#define NBUCK 391                // ceil(100000/256) coarse buckets (256 nodes each)
#define BCAP 6144                // slots per bucket (mean 4608, sd 66 -> +23 sigma)
#define NBB 640                  // bin-pass blocks
#define EPB ((ET + NBB - 1) / NBB)

typedef __hip_bfloat16 bf16;
typedef __attribute__((ext_vector_type(8))) short s8v;          // 8 bf16 MFMA A/B frag
typedef __attribute__((ext_vector_type(4))) float f4v;          // MFMA C/D frag
typedef __attribute__((ext_vector_type(4))) unsigned int u4v;
typedef __attribute__((ext_vector_type(2))) unsigned int u2v;

__device__ __forceinline__ float b2f(bf16 v){ return __bfloat162float(v); }
__device__ __forceinline__ float rdf(const void* p, size_t i, int isb){
    return isb ? b2f(((const bf16*)p)[i]) : ((const float*)p)[i];
}
__device__ __forceinline__ unsigned short f2bb(float v){
    bf16 h = __float2bfloat16(v);
    return *(unsigned short*)&h;
}
__device__ __forceinline__ uint32_t pack2(float a, float b){
    return (uint32_t)f2bb(a) | ((uint32_t)f2bb(b) << 16);
}
__device__ __forceinline__ float lo16(uint32_t u){ return __uint_as_float(u << 16); }
__device__ __forceinline__ float hi16(uint32_t u){ return __uint_as_float(u & 0xFFFF0000u); }
__device__ __forceinline__ float hcvt(uint32_t w, int sh){
    return __half2float(__ushort_as_half((unsigned short)((w >> sh) & 0xFFFFu)));
}

// ---------------- dtype detector --------------------------------------------
__global__ __launch_bounds__(256) void k_detect(
    const uint32_t* __restrict__ w1bits, int* __restrict__ flag)
{
    __shared__ int cnt;
    int t = threadIdx.x;
    if (t == 0) cnt = 0;
    __syncthreads();
    uint32_t b = w1bits[t];
    float lo = __uint_as_float((b & 0xFFFFu) << 16);
    float a = fabsf(lo);
    if (a > 1e-8f && a < 1.0f) atomicAdd(&cnt, 1);
    __syncthreads();
    if (t == 0) *flag = (cnt >= 192) ? 1 : 0;
}

// ---------------- GEMM1 (MFMA): h1 = x @ W1, + fused att1 dots --------------
__global__ __launch_bounds__(256) void k_gemm1(
    const void* __restrict__ x, const void* __restrict__ W1,
    const void* __restrict__ attS, const void* __restrict__ attD,
    const int* __restrict__ flag, unsigned short* __restrict__ h1,
    float* __restrict__ aS, float* __restrict__ aD)
{
    __shared__ __attribute__((aligned(16))) unsigned short wT[128*132]; // 33.8 KB
    const int isb = *flag;
    const int tid = threadIdx.x;
    if (isb) {
        const unsigned short* w = (const unsigned short*)W1;
        for (int idx = tid; idx < 128*128; idx += 256){
            int k = idx >> 7, n = idx & 127;
            wT[n*132 + k] = w[idx];
        }
    } else {
        const float* w = (const float*)W1;
        for (int idx = tid; idx < 128*128; idx += 256){
            int k = idx >> 7, n = idx & 127;
            wT[n*132 + k] = f2bb(w[idx]);
        }
    }
    __syncthreads();

    const int w4 = tid >> 6, lane = tid & 63, quad = lane >> 4, l16 = lane & 15;
    const int rowbase = blockIdx.x*32 + (w4 >> 1)*16;   // 3125*32 = 100000 exact
    const int colbase = (w4 & 1)*64;
    const int head = w4 & 1;

    s8v bfr[4][4];
    float asv[4], adv[4];
    #pragma unroll
    for (int ct = 0; ct < 4; ct++){
        int n = colbase + ct*16 + l16;
        asv[ct] = rdf(attS, n, isb);
        adv[ct] = rdf(attD, n, isb);
        #pragma unroll
        for (int s = 0; s < 4; s++){
            int k0 = s*32 + quad*8;
            const unsigned short* p = &wT[n*132 + k0];
            u2v a = *(const u2v*)p, b = *(const u2v*)(p+4);
            union { u4v u; s8v s; } cv; cv.u = (u4v){a[0],a[1],b[0],b[1]};
            bfr[ct][s] = cv.s;
        }
    }

    f4v acc[4];
    #pragma unroll
    for (int ct = 0; ct < 4; ct++) acc[ct] = (f4v){0.f,0.f,0.f,0.f};

    const int m = rowbase + l16;
    #pragma unroll
    for (int s = 0; s < 4; s++){
        int k0 = s*32 + quad*8;
        s8v af;
        if (isb){
            union { u4v u; s8v s; } cv;
            cv.u = *(const u4v*)((const unsigned short*)x + (size_t)m*128 + k0);
            af = cv.s;
        } else {
            const float* xp = (const float*)x + (size_t)m*128 + k0;
            f4v f0 = *(const f4v*)xp, f1 = *(const f4v*)(xp+4);
            union { u4v u; s8v s; } cv;
            cv.u = (u4v){pack2(f0[0],f0[1]), pack2(f0[2],f0[3]),
                         pack2(f1[0],f1[1]), pack2(f1[2],f1[3])};
            af = cv.s;
        }
        #pragma unroll
        for (int ct = 0; ct < 4; ct++)
            acc[ct] = __builtin_amdgcn_mfma_f32_16x16x32_bf16(af, bfr[ct][s], acc[ct], 0,0,0);
    }

    // C/D: col = lane&15, row = quad*4 + reg
    #pragma unroll
    for (int ct = 0; ct < 4; ct++){
        int col = colbase + ct*16 + l16;
        #pragma unroll
        for (int r = 0; r < 4; r++){
            int row = rowbase + quad*4 + r;
            h1[(size_t)row*128 + col] = f2bb(acc[ct][r]);
        }
    }

    // fused att1: per row, reduce acc*att over wave's 64 cols (one head).
    #pragma unroll
    for (int r = 0; r < 4; r++){
        float vs = 0.f, vd = 0.f;
        #pragma unroll
        for (int ct = 0; ct < 4; ct++){ vs += acc[ct][r]*asv[ct]; vd += acc[ct][r]*adv[ct]; }
        #pragma unroll
        for (int o = 1; o < 16; o <<= 1){
            vs += __shfl_xor(vs, o, 64);
            vd += __shfl_xor(vd, o, 64);
        }
        if (l16 == 0){
            int row = rowbase + quad*4 + r;
            aS[row*2 + head] = vs;
            aD[row*2 + head] = vd;
        }
    }
}

// ---------------- CSR pass 1: LDS-binned coarse scatter ---------------------
__global__ __launch_bounds__(256) void k_bin(
    const int* __restrict__ esrc, const int* __restrict__ edst,
    int* __restrict__ gcur, uint32_t* __restrict__ staging)
{
    __shared__ int cnt[NBUCK];
    __shared__ int bb[NBUCK];
    const int t = threadIdx.x;
    for (int i = t; i < NBUCK; i += 256) cnt[i] = 0;
    __syncthreads();
    const int e0 = blockIdx.x * EPB;
    const int e1 = (e0 + EPB < ET) ? e0 + EPB : ET;
    for (int e = e0 + t; e < e1; e += 256){
        int d = (e < N_EDGES) ? edst[e] : e - N_EDGES;
        atomicAdd(&cnt[d >> 8], 1);
    }
    __syncthreads();
    for (int i = t; i < NBUCK; i += 256){
        int c = cnt[i];
        bb[i] = c ? atomicAdd(&gcur[i], c) : 0;
        cnt[i] = 0;
    }
    __syncthreads();
    for (int e = e0 + t; e < e1; e += 256){
        int d, s;
        if (e < N_EDGES){ s = esrc[e]; d = edst[e]; } else { s = d = e - N_EDGES; }
        int b = d >> 8;
        int r = atomicAdd(&cnt[b], 1);
        int p = bb[b] + r;
        if (p < BCAP) staging[(size_t)b*BCAP + p] = ((uint32_t)s << 8) | (uint32_t)(d & 255);
    }
}

// ---------------- CSR pass 2: per-bucket fine counting sort -----------------
__global__ __launch_bounds__(256) void k_sort(
    const int* __restrict__ gcur, const uint32_t* __restrict__ staging,
    int* __restrict__ deg, int* __restrict__ cur, int* __restrict__ eidx)
{
    __shared__ int h[256], sc[256], rk[256];
    __shared__ int lsrc[BCAP];
    const int b = blockIdx.x;
    const int t = threadIdx.x;
    const int base = b * BCAP;
    int cnt = gcur[b];
    if (cnt > BCAP) cnt = BCAP;
    h[t] = 0; rk[t] = 0;
    __syncthreads();
    for (int i = t; i < cnt; i += 256)
        atomicAdd(&h[staging[base + i] & 255u], 1);
    __syncthreads();
    sc[t] = h[t];
    __syncthreads();
    for (int off = 1; off < 256; off <<= 1){
        int v = (t >= off) ? sc[t - off] : 0;
        __syncthreads();
        sc[t] += v;
        __syncthreads();
    }
    int dg = b*256 + t;
    if (dg < N_NODES){
        deg[dg] = h[t];
        cur[dg] = base + sc[t];    // end pointer; start = end - deg
    }
    __syncthreads();
    for (int i = t; i < cnt; i += 256){
        uint32_t w = staging[base + i];
        int dl = w & 255u;
        int r = atomicAdd(&rk[dl], 1);
        lsrc[sc[dl] - h[dl] + r] = (int)(w >> 8);
    }
    __syncthreads();
    for (int i = t; i < cnt; i += 256) eidx[base + i] = lsrc[i];
}

// ---------------- edge weights: one wave per node, pre-normalized half2 -----
__global__ __launch_bounds__(256) void k_ew(
    const int* __restrict__ cur, const int* __restrict__ deg,
    const int* __restrict__ eidx, const float* __restrict__ aS,
    const float* __restrict__ aD, uint32_t* __restrict__ wgt)
{
    int d = blockIdx.x*4 + (threadIdx.x >> 6);
    if (d >= N_NODES) return;
    int l = threadIdx.x & 63;
    int end   = __builtin_amdgcn_readfirstlane(cur[d]);
    int start = end - __builtin_amdgcn_readfirstlane(deg[d]);
    float2 ad = *(const float2*)(aD + d*2);
    float den0 = 0.f, den1 = 0.f;
    for (int j0 = start; j0 < end; j0 += 64){
        int j = j0 + l;
        float e0 = 0.f, e1 = 0.f;
        if (j < end){
            int s = eidx[j];
            float2 as = *(const float2*)(aS + s*2);
            float al0 = as.x + ad.x, al1 = as.y + ad.y;
            al0 = al0 > 0.f ? al0 : NEG*al0;
            al1 = al1 > 0.f ? al1 : NEG*al1;
            e0 = __expf(al0); e1 = __expf(al1);
        }
        den0 += e0; den1 += e1;
    }
    #pragma unroll
    for (int o = 1; o < 64; o <<= 1){
        den0 += __shfl_xor(den0, o, 64);
        den1 += __shfl_xor(den1, o, 64);
    }
    float i0 = 1.f / fmaxf(den0, 1e-20f);
    float i1 = 1.f / fmaxf(den1, 1e-20f);
    for (int j0 = start; j0 < end; j0 += 64){
        int j = j0 + l;
        if (j < end){
            int s = eidx[j];
            float2 as = *(const float2*)(aS + s*2);
            float al0 = as.x + ad.x, al1 = as.y + ad.y;
            al0 = al0 > 0.f ? al0 : NEG*al0;
            al1 = al1 > 0.f ? al1 : NEG*al1;
            unsigned short p0 = __half_as_ushort(__float2half(__expf(al0) * i0));
            unsigned short p1 = __half_as_ushort(__float2half(__expf(al1) * i1));
            wgt[j] = (uint32_t)p0 | ((uint32_t)p1 << 16);
        }
    }
}

// ---------------- layer-1 aggregation: one node per wave, lean loop ---------
__global__ __launch_bounds__(256) void k_agg1(
    const int* __restrict__ cur, const int* __restrict__ deg,
    const int* __restrict__ eidx, const uint32_t* __restrict__ wgt,
    const uint32_t* __restrict__ h1u, uint32_t* __restrict__ out1u)
{
    int d = blockIdx.x*4 + (threadIdx.x >> 6);
    if (d >= N_NODES) return;
    int l = threadIdx.x & 63;            // lane: feats 2l,2l+1; head = l>=32
    int end = __builtin_amdgcn_readfirstlane(cur[d]);
    int j   = end - __builtin_amdgcn_readfirstlane(deg[d]);
    const int sh = (l >= 32) ? 16 : 0;
    float acc0 = 0.f, acc1 = 0.f;

#define P1(W, G) { float Wf = hcvt(W, sh); \
    acc0 += Wf * lo16(G); acc1 += Wf * hi16(G); }

    for (; j + 4 <= end; j += 4){
        int s0 = eidx[j], s1 = eidx[j+1], s2 = eidx[j+2], s3 = eidx[j+3];
        uint32_t w0 = wgt[j], w1 = wgt[j+1], w2 = wgt[j+2], w3 = wgt[j+3];
        uint32_t g0 = h1u[(size_t)s0*64 + l];
        uint32_t g1 = h1u[(size_t)s1*64 + l];
        uint32_t g2 = h1u[(size_t)s2*64 + l];
        uint32_t g3 = h1u[(size_t)s3*64 + l];
        P1(w0, g0); P1(w1, g1); P1(w2, g2); P1(w3, g3);
    }
    for (; j < end; j++){
        int s = eidx[j];
        uint32_t w = wgt[j];
        uint32_t g = h1u[(size_t)s*64 + l];
        P1(w, g);
    }
#undef P1
    out1u[(size_t)d*64 + l] = pack2(acc0, acc1);
}

// ---------------- BatchNorm stats -------------------------------------------
__global__ __launch_bounds__(256) void k_bnstats(
    const uint32_t* __restrict__ out1u, float* __restrict__ stats)
{
    int fp = threadIdx.x & 63;
    int r0 = blockIdx.x*4 + (threadIdx.x >> 6);
    float s0 = 0.f, q0 = 0.f, s1 = 0.f, q1 = 0.f;
    for (int r = r0; r < N_NODES; r += 2048){
        uint32_t u = out1u[(size_t)r*64 + fp];
        float f0 = lo16(u), f1 = hi16(u);
        s0 += f0; q0 += f0*f0; s1 += f1; q1 += f1*f1;
    }
    unsafeAtomicAdd(&stats[2*fp],       s0);
    unsafeAtomicAdd(&stats[2*fp+1],     s1);
    unsafeAtomicAdd(&stats[128+2*fp],   q0);
    unsafeAtomicAdd(&stats[128+2*fp+1], q1);
}

// ---------------- GEMM2 (MFMA): h2 = BN(out1) @ W2, + fused att2, BN-fin ----
__global__ __launch_bounds__(256) void k_gemm2(
    const unsigned short* __restrict__ out1b, const float* __restrict__ stats,
    const void* __restrict__ gamma, const void* __restrict__ beta,
    const void* __restrict__ W2, const void* __restrict__ attS,
    const void* __restrict__ attD, const int* __restrict__ flag,
    unsigned short* __restrict__ h2, float* __restrict__ aS, float* __restrict__ aD)
{
    __shared__ __attribute__((aligned(16))) unsigned short wT[80*132]; // 21.1 KB
    __shared__ float scl[128], shl[128];
    const int isb = *flag;
    const int tid = threadIdx.x;
    for (int idx = tid; idx < 128*80; idx += 256){
        int k = idx / 80, n = idx - k*80;
        wT[n*132 + k] = isb ? ((const unsigned short*)W2)[idx]
                            : f2bb(((const float*)W2)[idx]);
    }
    if (tid < 128){   // inline BN finalize
        float mean = stats[tid] * (1.f / N_NODES);
        float var = fmaxf(stats[128+tid] * (1.f / N_NODES) - mean*mean, 0.f);
        float rs = rsqrtf(var + BN_EPS);
        float sc = rdf(gamma, tid, isb) * rs;
        scl[tid] = sc;
        shl[tid] = rdf(beta, tid, isb) - mean*sc;
    }
    __syncthreads();

    const int w4 = tid >> 6, lane = tid & 63, quad = lane >> 4, l16 = lane & 15;
    const int rowbase = blockIdx.x*64 + w4*16;

    s8v bfr[5][4];
    float asv[5], adv[5];
    #pragma unroll
    for (int ct = 0; ct < 5; ct++){
        int n = ct*16 + l16;
        asv[ct] = rdf(attS, n, isb);
        adv[ct] = rdf(attD, n, isb);
        #pragma unroll
        for (int s = 0; s < 4; s++){
            int k0 = s*32 + quad*8;
            const unsigned short* p = &wT[n*132 + k0];
            u2v a = *(const u2v*)p, b = *(const u2v*)(p+4);
            union { u4v u; s8v s; } cv; cv.u = (u4v){a[0],a[1],b[0],b[1]};
            bfr[ct][s] = cv.s;
        }
    }

    f4v acc[5];
    #pragma unroll
    for (int ct = 0; ct < 5; ct++) acc[ct] = (f4v){0.f,0.f,0.f,0.f};

    int m = rowbase + l16;
    int mc = m < N_NODES ? m : N_NODES - 1;
    #pragma unroll
    for (int s = 0; s < 4; s++){
        int k0 = s*32 + quad*8;
        union { u4v u; s8v s8; } cin;
        cin.u = *(const u4v*)(out1b + (size_t)mc*128 + k0);
        u4v up;
        #pragma unroll
        for (int i = 0; i < 4; i++){
            float f0 = lo16(cin.u[i]), f1 = hi16(cin.u[i]);
            int k = k0 + 2*i;
            up[i] = pack2(f0*scl[k] + shl[k], f1*scl[k+1] + shl[k+1]);
        }
        union { u4v u; s8v s8; } cv; cv.u = up;
        #pragma unroll
        for (int ct = 0; ct < 5; ct++)
            acc[ct] = __builtin_amdgcn_mfma_f32_16x16x32_bf16(cv.s8, bfr[ct][s], acc[ct], 0,0,0);
    }

    #pragma unroll
    for (int ct = 0; ct < 5; ct++){
        int col = ct*16 + l16;
        #pragma unroll
        for (int r = 0; r < 4; r++){
            int row = rowbase + quad*4 + r;
            if (row < N_NODES) h2[(size_t)row*80 + col] = f2bb(acc[ct][r]);
        }
    }

    // fused att2: head0 = cols 0..39, head1 = cols 40..79.
    #pragma unroll
    for (int r = 0; r < 4; r++){
        float vs0 = 0.f, vs1 = 0.f, vd0 = 0.f, vd1 = 0.f;
        #pragma unroll
        for (int ct = 0; ct < 5; ct++){
            int col = ct*16 + l16;
            float ps = acc[ct][r]*asv[ct], pd = acc[ct][r]*adv[ct];
            if (col < 40){ vs0 += ps; vd0 += pd; } else { vs1 += ps; vd1 += pd; }
        }
        #pragma unroll
        for (int o = 1; o < 16; o <<= 1){
            vs0 += __shfl_xor(vs0, o, 64); vs1 += __shfl_xor(vs1, o, 64);
            vd0 += __shfl_xor(vd0, o, 64); vd1 += __shfl_xor(vd1, o, 64);
        }
        if (l16 == 0){
            int row = rowbase + quad*4 + r;
            if (row < N_NODES){
                aS[row*2 + 0] = vs0; aS[row*2 + 1] = vs1;
                aD[row*2 + 0] = vd0; aD[row*2 + 1] = vd1;
            }
        }
    }
}

// ---------------- layer-2 aggregation + fused head-mean/log_softmax ---------
__global__ __launch_bounds__(256) void k_agg2(
    const int* __restrict__ cur, const int* __restrict__ deg,
    const int* __restrict__ eidx, const uint32_t* __restrict__ wgt,
    const uint32_t* __restrict__ h2u, const void* __restrict__ b2v,
    const int* __restrict__ flag, void* __restrict__ out)
{
    int d = blockIdx.x*4 + (threadIdx.x >> 6);
    if (d >= N_NODES) return;
    int l = threadIdx.x & 63;
    if (l >= 40) return;                 // lane covers u32 l: feats 2l,2l+1; head = l>=20
    const int isb = *flag;
    int end = __builtin_amdgcn_readfirstlane(cur[d]);
    int j   = end - __builtin_amdgcn_readfirstlane(deg[d]);
    const int sh = (l >= 20) ? 16 : 0;
    float acc0 = 0.f, acc1 = 0.f;

#define P2(W, G) { float Wf = hcvt(W, sh); \
    acc0 += Wf * lo16(G); acc1 += Wf * hi16(G); }

    for (; j + 4 <= end; j += 4){
        int s0 = eidx[j], s1 = eidx[j+1], s2 = eidx[j+2], s3 = eidx[j+3];
        uint32_t w0 = wgt[j], w1 = wgt[j+1], w2 = wgt[j+2], w3 = wgt[j+3];
        uint32_t g0 = h2u[(size_t)s0*40 + l];
        uint32_t g1 = h2u[(size_t)s1*40 + l];
        uint32_t g2 = h2u[(size_t)s2*40 + l];
        uint32_t g3 = h2u[(size_t)s3*40 + l];
        P2(w0, g0); P2(w1, g1); P2(w2, g2); P2(w3, g3);
    }
    for (; j < end; j++){
        int s = eidx[j];
        uint32_t w = wgt[j];
        uint32_t g = h2u[(size_t)s*40 + l];
        P2(w, g);
    }
#undef P2

    // head-mean: lane l<20 combines its pair (head0) with lane l+20 (head1).
    float m0 = 0.5f*(acc0 + __shfl(acc0, l + 20, 64));
    float m1 = 0.5f*(acc1 + __shfl(acc1, l + 20, 64));
    float v0 = -1e30f, v1 = -1e30f;
    if (l < 20){
        v0 = m0 + rdf(b2v, 2*l,   isb);
        v1 = m1 + rdf(b2v, 2*l+1, isb);
    }
    // log_softmax over 40 classes held in lanes 0..19 (lanes 20..31 neutral).
    float mx = fmaxf(v0, v1);
    #pragma unroll
    for (int o = 1; o < 32; o <<= 1) mx = fmaxf(mx, __shfl_xor(mx, o, 64));
    float ex = (l < 20) ? __expf(v0 - mx) + __expf(v1 - mx) : 0.f;
    #pragma unroll
    for (int o = 1; o < 32; o <<= 1) ex += __shfl_xor(ex, o, 64);
    float lse = __logf(ex);
    if (l < 20){
        float r0 = v0 - mx - lse, r1 = v1 - mx - lse;
        if (isb){
            ((uint32_t*)out)[(size_t)d*20 + l] = pack2(r0, r1);
        } else {
            float2 wr; wr.x = r0; wr.y = r1;
            ((float2*)out)[(size_t)d*20 + l] = wr;
        }
    }
}

extern "C" void kernel_launch(void* const* d_in, const int* in_sizes, int n_in,
                              void* d_out, int out_size, void* d_ws, size_t ws_size,
                              hipStream_t stream)
{
    const void* x    = d_in[0];
    const int*  ei   = (const int*)d_in[1];
    const void* W1   = d_in[2];
    const void* as1  = d_in[3];
    const void* ad1  = d_in[4];
    // d_in[5] = b1: cancels exactly through BatchNorm mean subtraction
    const void* gamma = d_in[6];
    const void* beta  = d_in[7];
    const void* W2   = d_in[8];
    const void* as2  = d_in[9];
    const void* ad2  = d_in[10];
    const void* b2v  = d_in[11];
    const int* esrc = ei;
    const int* edst = ei + N_EDGES;

    // --- workspace: ~75 MB total (81.7 MB proven safe) ---
    char* ws = (char*)d_ws;
    size_t off = 0;
    auto alloc = [&](size_t bytes) {
        void* p = ws + off;
        off += (bytes + 255) & ~(size_t)255;
        return p;
    };
    int*   flag  = (int*)alloc(256);
    float* stats = (float*)alloc(sizeof(float)*256);
    int*   gcur  = (int*)alloc(sizeof(int)*NBUCK);
    float* aS1   = (float*)alloc(sizeof(float)*N_NODES*2);
    float* aD1   = (float*)alloc(sizeof(float)*N_NODES*2);
    float* aS2   = (float*)alloc(sizeof(float)*N_NODES*2);
    float* aD2   = (float*)alloc(sizeof(float)*N_NODES*2);
    int*   deg   = (int*)alloc(sizeof(int)*N_NODES);
    int*   cur   = (int*)alloc(sizeof(int)*N_NODES);
    uint32_t* staging = (uint32_t*)alloc(sizeof(uint32_t)*(size_t)NBUCK*BCAP); // 9.6 MB
    int*   eidx  = (int*)alloc(sizeof(int)*(size_t)NBUCK*BCAP);                // 9.6 MB
    unsigned short* h1  = (unsigned short*)alloc(2*(size_t)N_NODES*HID);  // 25.6 MB
    unsigned short* out1 = (unsigned short*)alloc(2*(size_t)N_NODES*HID); // 25.6 MB
    unsigned short* h2  = h1;            // alias: h1 dead after k_agg1
    uint32_t* wgt = staging;             // alias: staging dead after k_sort

    hipMemsetAsync(gcur, 0, sizeof(int)*NBUCK, stream);
    hipMemsetAsync(stats, 0, sizeof(float)*256, stream);

    k_detect<<<1, 256, 0, stream>>>((const uint32_t*)W1, flag);
    k_gemm1<<<3125, 256, 0, stream>>>(x, W1, as1, ad1, flag, h1, aS1, aD1);
    k_bin<<<NBB, 256, 0, stream>>>(esrc, edst, gcur, staging);
    k_sort<<<NBUCK, 256, 0, stream>>>(gcur, staging, deg, cur, eidx);
    k_ew<<<25000, 256, 0, stream>>>(cur, deg, eidx, aS1, aD1, wgt);
    k_agg1<<<25000, 256, 0, stream>>>(cur, deg, eidx, wgt,
                                      (const uint32_t*)h1, (uint32_t*)out1);
    k_bnstats<<<512, 256, 0, stream>>>((const uint32_t*)out1, stats);
    k_gemm2<<<1563, 256, 0, stream>>>(out1, stats, gamma, beta, W2, as2, ad2,
                                      flag, h2, aS2, aD2);
    k_ew<<<25000, 256, 0, stream>>>(cur, deg, eidx, aS2, aD2, wgt);
    k_agg2<<<25000, 256, 0, stream>>>(cur, deg, eidx, wgt,
                                      (const uint32_t*)h2, b2v, flag, d_out);
}

// Round 9
// 478.523 us; speedup vs baseline: 1.1094x; 1.1094x over previous
//
#include <hip/hip_runtime.h>
#include <hip/hip_bf16.h>
#include <hip/hip_fp16.h>
#include <stdint.h>

#define N_NODES 100000
#define N_EDGES 1600000
#define ET (N_EDGES + N_NODES)   // edges + self-loops
#define HID 128
#define C2 40
#define F2 80
#define NEG 0.2f
#define BN_EPS 1e-5f
#define NBUCK 391                // ceil(100000/256) coarse buckets (256 nodes each)
#define BCAP 6144                // slots per bucket (mean 4608, sd 66 -> +23 sigma)
#define NBB 640                  // bin-pass blocks
#define EPB ((ET + NBB - 1) / NBB)

typedef __hip_bfloat16 bf16;
typedef __attribute__((ext_vector_type(8))) short s8v;          // 8 bf16 MFMA A/B frag
typedef __attribute__((ext_vector_type(4))) float f4v;          // MFMA C/D frag
typedef __attribute__((ext_vector_type(4))) unsigned int u4v;
typedef __attribute__((ext_vector_type(2))) unsigned int u2v;

__device__ __forceinline__ float b2f(bf16 v){ return __bfloat162float(v); }
__device__ __forceinline__ float rdf(const void* p, size_t i, int isb){
    return isb ? b2f(((const bf16*)p)[i]) : ((const float*)p)[i];
}
__device__ __forceinline__ unsigned short f2bb(float v){
    bf16 h = __float2bfloat16(v);
    return *(unsigned short*)&h;
}
__device__ __forceinline__ uint32_t pack2(float a, float b){
    return (uint32_t)f2bb(a) | ((uint32_t)f2bb(b) << 16);
}
__device__ __forceinline__ float lo16(uint32_t u){ return __uint_as_float(u << 16); }
__device__ __forceinline__ float hi16(uint32_t u){ return __uint_as_float(u & 0xFFFF0000u); }
__device__ __forceinline__ float hcvt(uint32_t w, int sh){
    return __half2float(__ushort_as_half((unsigned short)((w >> sh) & 0xFFFFu)));
}

// ---------------- dtype detector --------------------------------------------
__global__ __launch_bounds__(256) void k_detect(
    const uint32_t* __restrict__ w1bits, int* __restrict__ flag)
{
    __shared__ int cnt;
    int t = threadIdx.x;
    if (t == 0) cnt = 0;
    __syncthreads();
    uint32_t b = w1bits[t];
    float lo = __uint_as_float((b & 0xFFFFu) << 16);
    float a = fabsf(lo);
    if (a > 1e-8f && a < 1.0f) atomicAdd(&cnt, 1);
    __syncthreads();
    if (t == 0) *flag = (cnt >= 192) ? 1 : 0;
}

// ---------------- GEMM1 (MFMA): h1 = x @ W1, + fused att1 dots --------------
__global__ __launch_bounds__(256) void k_gemm1(
    const void* __restrict__ x, const void* __restrict__ W1,
    const void* __restrict__ attS, const void* __restrict__ attD,
    const int* __restrict__ flag, unsigned short* __restrict__ h1,
    float* __restrict__ aS, float* __restrict__ aD)
{
    __shared__ __attribute__((aligned(16))) unsigned short wT[128*132]; // 33.8 KB
    const int isb = *flag;
    const int tid = threadIdx.x;
    if (isb) {
        const unsigned short* w = (const unsigned short*)W1;
        for (int idx = tid; idx < 128*128; idx += 256){
            int k = idx >> 7, n = idx & 127;
            wT[n*132 + k] = w[idx];
        }
    } else {
        const float* w = (const float*)W1;
        for (int idx = tid; idx < 128*128; idx += 256){
            int k = idx >> 7, n = idx & 127;
            wT[n*132 + k] = f2bb(w[idx]);
        }
    }
    __syncthreads();

    const int w4 = tid >> 6, lane = tid & 63, quad = lane >> 4, l16 = lane & 15;
    const int rowbase = blockIdx.x*32 + (w4 >> 1)*16;   // 3125*32 = 100000 exact
    const int colbase = (w4 & 1)*64;
    const int head = w4 & 1;

    s8v bfr[4][4];
    float asv[4], adv[4];
    #pragma unroll
    for (int ct = 0; ct < 4; ct++){
        int n = colbase + ct*16 + l16;
        asv[ct] = rdf(attS, n, isb);
        adv[ct] = rdf(attD, n, isb);
        #pragma unroll
        for (int s = 0; s < 4; s++){
            int k0 = s*32 + quad*8;
            const unsigned short* p = &wT[n*132 + k0];
            u2v a = *(const u2v*)p, b = *(const u2v*)(p+4);
            union { u4v u; s8v s; } cv; cv.u = (u4v){a[0],a[1],b[0],b[1]};
            bfr[ct][s] = cv.s;
        }
    }

    f4v acc[4];
    #pragma unroll
    for (int ct = 0; ct < 4; ct++) acc[ct] = (f4v){0.f,0.f,0.f,0.f};

    const int m = rowbase + l16;
    #pragma unroll
    for (int s = 0; s < 4; s++){
        int k0 = s*32 + quad*8;
        s8v af;
        if (isb){
            union { u4v u; s8v s; } cv;
            cv.u = *(const u4v*)((const unsigned short*)x + (size_t)m*128 + k0);
            af = cv.s;
        } else {
            const float* xp = (const float*)x + (size_t)m*128 + k0;
            f4v f0 = *(const f4v*)xp, f1 = *(const f4v*)(xp+4);
            union { u4v u; s8v s; } cv;
            cv.u = (u4v){pack2(f0[0],f0[1]), pack2(f0[2],f0[3]),
                         pack2(f1[0],f1[1]), pack2(f1[2],f1[3])};
            af = cv.s;
        }
        #pragma unroll
        for (int ct = 0; ct < 4; ct++)
            acc[ct] = __builtin_amdgcn_mfma_f32_16x16x32_bf16(af, bfr[ct][s], acc[ct], 0,0,0);
    }

    // C/D: col = lane&15, row = quad*4 + reg
    #pragma unroll
    for (int ct = 0; ct < 4; ct++){
        int col = colbase + ct*16 + l16;
        #pragma unroll
        for (int r = 0; r < 4; r++){
            int row = rowbase + quad*4 + r;
            h1[(size_t)row*128 + col] = f2bb(acc[ct][r]);
        }
    }

    // fused att1: per row, reduce acc*att over wave's 64 cols (one head).
    #pragma unroll
    for (int r = 0; r < 4; r++){
        float vs = 0.f, vd = 0.f;
        #pragma unroll
        for (int ct = 0; ct < 4; ct++){ vs += acc[ct][r]*asv[ct]; vd += acc[ct][r]*adv[ct]; }
        #pragma unroll
        for (int o = 1; o < 16; o <<= 1){
            vs += __shfl_xor(vs, o, 64);
            vd += __shfl_xor(vd, o, 64);
        }
        if (l16 == 0){
            int row = rowbase + quad*4 + r;
            aS[row*2 + head] = vs;
            aD[row*2 + head] = vd;
        }
    }
}

// ---------------- CSR pass 1: LDS-binned coarse scatter ---------------------
__global__ __launch_bounds__(256) void k_bin(
    const int* __restrict__ esrc, const int* __restrict__ edst,
    int* __restrict__ gcur, uint32_t* __restrict__ staging)
{
    __shared__ int cnt[NBUCK];
    __shared__ int bb[NBUCK];
    const int t = threadIdx.x;
    for (int i = t; i < NBUCK; i += 256) cnt[i] = 0;
    __syncthreads();
    const int e0 = blockIdx.x * EPB;
    const int e1 = (e0 + EPB < ET) ? e0 + EPB : ET;
    for (int e = e0 + t; e < e1; e += 256){
        int d = (e < N_EDGES) ? edst[e] : e - N_EDGES;
        atomicAdd(&cnt[d >> 8], 1);
    }
    __syncthreads();
    // rotate flush order by block to avoid lockstep per-address atomic chains
    const int bofs = (int)(blockIdx.x % NBUCK);
    for (int i = t; i < NBUCK; i += 256){
        int bkt = i + bofs; if (bkt >= NBUCK) bkt -= NBUCK;
        int c = cnt[bkt];
        bb[bkt] = c ? atomicAdd(&gcur[bkt], c) : 0;
        cnt[bkt] = 0;
    }
    __syncthreads();
    for (int e = e0 + t; e < e1; e += 256){
        int d, s;
        if (e < N_EDGES){ s = esrc[e]; d = edst[e]; } else { s = d = e - N_EDGES; }
        int b = d >> 8;
        int r = atomicAdd(&cnt[b], 1);
        int p = bb[b] + r;
        if (p < BCAP) staging[(size_t)b*BCAP + p] = ((uint32_t)s << 8) | (uint32_t)(d & 255);
    }
}

// ---------------- CSR pass 2: per-bucket fine counting sort -----------------
__global__ __launch_bounds__(256) void k_sort(
    const int* __restrict__ gcur, const uint32_t* __restrict__ staging,
    int* __restrict__ deg, int* __restrict__ cur, int* __restrict__ eidx)
{
    __shared__ int h[256], sc[256], rk[256];
    __shared__ int lsrc[BCAP];
    const int b = blockIdx.x;
    const int t = threadIdx.x;
    const int base = b * BCAP;
    int cnt = gcur[b];
    if (cnt > BCAP) cnt = BCAP;
    h[t] = 0; rk[t] = 0;
    __syncthreads();
    for (int i = t; i < cnt; i += 256)
        atomicAdd(&h[staging[base + i] & 255u], 1);
    __syncthreads();
    sc[t] = h[t];
    __syncthreads();
    for (int off = 1; off < 256; off <<= 1){
        int v = (t >= off) ? sc[t - off] : 0;
        __syncthreads();
        sc[t] += v;
        __syncthreads();
    }
    int dg = b*256 + t;
    if (dg < N_NODES){
        deg[dg] = h[t];
        cur[dg] = base + sc[t];    // end pointer; start = end - deg
    }
    __syncthreads();
    for (int i = t; i < cnt; i += 256){
        uint32_t w = staging[base + i];
        int dl = w & 255u;
        int r = atomicAdd(&rk[dl], 1);
        lsrc[sc[dl] - h[dl] + r] = (int)(w >> 8);
    }
    __syncthreads();
    for (int i = t; i < cnt; i += 256) eidx[base + i] = lsrc[i];
}

// ---------------- edge weights: one wave per node, pre-normalized half2 -----
__global__ __launch_bounds__(256) void k_ew(
    const int* __restrict__ cur, const int* __restrict__ deg,
    const int* __restrict__ eidx, const float* __restrict__ aS,
    const float* __restrict__ aD, uint32_t* __restrict__ wgt)
{
    int d = blockIdx.x*4 + (threadIdx.x >> 6);
    if (d >= N_NODES) return;
    int l = threadIdx.x & 63;
    int end   = __builtin_amdgcn_readfirstlane(cur[d]);
    int start = end - __builtin_amdgcn_readfirstlane(deg[d]);
    float2 ad = *(const float2*)(aD + d*2);
    float den0 = 0.f, den1 = 0.f;
    for (int j0 = start; j0 < end; j0 += 64){
        int j = j0 + l;
        float e0 = 0.f, e1 = 0.f;
        if (j < end){
            int s = eidx[j];
            float2 as = *(const float2*)(aS + s*2);
            float al0 = as.x + ad.x, al1 = as.y + ad.y;
            al0 = al0 > 0.f ? al0 : NEG*al0;
            al1 = al1 > 0.f ? al1 : NEG*al1;
            e0 = __expf(al0); e1 = __expf(al1);
        }
        den0 += e0; den1 += e1;
    }
    #pragma unroll
    for (int o = 1; o < 64; o <<= 1){
        den0 += __shfl_xor(den0, o, 64);
        den1 += __shfl_xor(den1, o, 64);
    }
    float i0 = 1.f / fmaxf(den0, 1e-20f);
    float i1 = 1.f / fmaxf(den1, 1e-20f);
    for (int j0 = start; j0 < end; j0 += 64){
        int j = j0 + l;
        if (j < end){
            int s = eidx[j];
            float2 as = *(const float2*)(aS + s*2);
            float al0 = as.x + ad.x, al1 = as.y + ad.y;
            al0 = al0 > 0.f ? al0 : NEG*al0;
            al1 = al1 > 0.f ? al1 : NEG*al1;
            unsigned short p0 = __half_as_ushort(__float2half(__expf(al0) * i0));
            unsigned short p1 = __half_as_ushort(__float2half(__expf(al1) * i1));
            wgt[j] = (uint32_t)p0 | ((uint32_t)p1 << 16);
        }
    }
}

// ---------------- layer-1 aggregation: one node per wave, lean loop ---------
__global__ __launch_bounds__(256) void k_agg1(
    const int* __restrict__ cur, const int* __restrict__ deg,
    const int* __restrict__ eidx, const uint32_t* __restrict__ wgt,
    const uint32_t* __restrict__ h1u, uint32_t* __restrict__ out1u)
{
    int d = blockIdx.x*4 + (threadIdx.x >> 6);
    if (d >= N_NODES) return;
    int l = threadIdx.x & 63;            // lane: feats 2l,2l+1; head = l>=32
    int end = __builtin_amdgcn_readfirstlane(cur[d]);
    int j   = end - __builtin_amdgcn_readfirstlane(deg[d]);
    const int sh = (l >= 32) ? 16 : 0;
    float acc0 = 0.f, acc1 = 0.f;

#define P1(W, G) { float Wf = hcvt(W, sh); \
    acc0 += Wf * lo16(G); acc1 += Wf * hi16(G); }

    for (; j + 4 <= end; j += 4){
        int s0 = eidx[j], s1 = eidx[j+1], s2 = eidx[j+2], s3 = eidx[j+3];
        uint32_t w0 = wgt[j], w1 = wgt[j+1], w2 = wgt[j+2], w3 = wgt[j+3];
        uint32_t g0 = h1u[(size_t)s0*64 + l];
        uint32_t g1 = h1u[(size_t)s1*64 + l];
        uint32_t g2 = h1u[(size_t)s2*64 + l];
        uint32_t g3 = h1u[(size_t)s3*64 + l];
        P1(w0, g0); P1(w1, g1); P1(w2, g2); P1(w3, g3);
    }
    for (; j < end; j++){
        int s = eidx[j];
        uint32_t w = wgt[j];
        uint32_t g = h1u[(size_t)s*64 + l];
        P1(w, g);
    }
#undef P1
    out1u[(size_t)d*64 + l] = pack2(acc0, acc1);
}

// ---------------- BatchNorm stats: per-block LDS reduce, then 1 atomic ------
__global__ __launch_bounds__(256) void k_bnstats(
    const uint32_t* __restrict__ out1u, float* __restrict__ stats)
{
    __shared__ float red[4][64][4];      // wave x feat-pair x {s0,s1,q0,q1} = 4 KB
    int fp = threadIdx.x & 63;
    int wv = threadIdx.x >> 6;
    float s0 = 0.f, q0 = 0.f, s1 = 0.f, q1 = 0.f;
    for (int r = blockIdx.x*4 + wv; r < N_NODES; r += 512){
        uint32_t u = out1u[(size_t)r*64 + fp];
        float f0 = lo16(u), f1 = hi16(u);
        s0 += f0; q0 += f0*f0; s1 += f1; q1 += f1*f1;
    }
    red[wv][fp][0] = s0; red[wv][fp][1] = s1;
    red[wv][fp][2] = q0; red[wv][fp][3] = q1;
    __syncthreads();
    if (threadIdx.x < 64){
        int l = threadIdx.x;
        float a0=0.f, a1=0.f, b0=0.f, b1=0.f;
        #pragma unroll
        for (int w = 0; w < 4; w++){
            a0 += red[w][l][0]; a1 += red[w][l][1];
            b0 += red[w][l][2]; b1 += red[w][l][3];
        }
        unsafeAtomicAdd(&stats[2*l],       a0);
        unsafeAtomicAdd(&stats[2*l+1],     a1);
        unsafeAtomicAdd(&stats[128+2*l],   b0);
        unsafeAtomicAdd(&stats[128+2*l+1], b1);
    }
}

// ---------------- GEMM2 (MFMA): h2 = BN(out1) @ W2, + fused att2, BN-fin ----
__global__ __launch_bounds__(256) void k_gemm2(
    const unsigned short* __restrict__ out1b, const float* __restrict__ stats,
    const void* __restrict__ gamma, const void* __restrict__ beta,
    const void* __restrict__ W2, const void* __restrict__ attS,
    const void* __restrict__ attD, const int* __restrict__ flag,
    unsigned short* __restrict__ h2, float* __restrict__ aS, float* __restrict__ aD)
{
    __shared__ __attribute__((aligned(16))) unsigned short wT[80*132]; // 21.1 KB
    __shared__ float scl[128], shl[128];
    const int isb = *flag;
    const int tid = threadIdx.x;
    for (int idx = tid; idx < 128*80; idx += 256){
        int k = idx / 80, n = idx - k*80;
        wT[n*132 + k] = isb ? ((const unsigned short*)W2)[idx]
                            : f2bb(((const float*)W2)[idx]);
    }
    if (tid < 128){   // inline BN finalize
        float mean = stats[tid] * (1.f / N_NODES);
        float var = fmaxf(stats[128+tid] * (1.f / N_NODES) - mean*mean, 0.f);
        float rs = rsqrtf(var + BN_EPS);
        float sc = rdf(gamma, tid, isb) * rs;
        scl[tid] = sc;
        shl[tid] = rdf(beta, tid, isb) - mean*sc;
    }
    __syncthreads();

    const int w4 = tid >> 6, lane = tid & 63, quad = lane >> 4, l16 = lane & 15;
    const int rowbase = blockIdx.x*64 + w4*16;

    s8v bfr[5][4];
    float asv[5], adv[5];
    #pragma unroll
    for (int ct = 0; ct < 5; ct++){
        int n = ct*16 + l16;
        asv[ct] = rdf(attS, n, isb);
        adv[ct] = rdf(attD, n, isb);
        #pragma unroll
        for (int s = 0; s < 4; s++){
            int k0 = s*32 + quad*8;
            const unsigned short* p = &wT[n*132 + k0];
            u2v a = *(const u2v*)p, b = *(const u2v*)(p+4);
            union { u4v u; s8v s; } cv; cv.u = (u4v){a[0],a[1],b[0],b[1]};
            bfr[ct][s] = cv.s;
        }
    }

    f4v acc[5];
    #pragma unroll
    for (int ct = 0; ct < 5; ct++) acc[ct] = (f4v){0.f,0.f,0.f,0.f};

    int m = rowbase + l16;
    int mc = m < N_NODES ? m : N_NODES - 1;
    #pragma unroll
    for (int s = 0; s < 4; s++){
        int k0 = s*32 + quad*8;
        union { u4v u; s8v s8; } cin;
        cin.u = *(const u4v*)(out1b + (size_t)mc*128 + k0);
        u4v up;
        #pragma unroll
        for (int i = 0; i < 4; i++){
            float f0 = lo16(cin.u[i]), f1 = hi16(cin.u[i]);
            int k = k0 + 2*i;
            up[i] = pack2(f0*scl[k] + shl[k], f1*scl[k+1] + shl[k+1]);
        }
        union { u4v u; s8v s8; } cv; cv.u = up;
        #pragma unroll
        for (int ct = 0; ct < 5; ct++)
            acc[ct] = __builtin_amdgcn_mfma_f32_16x16x32_bf16(cv.s8, bfr[ct][s], acc[ct], 0,0,0);
    }

    #pragma unroll
    for (int ct = 0; ct < 5; ct++){
        int col = ct*16 + l16;
        #pragma unroll
        for (int r = 0; r < 4; r++){
            int row = rowbase + quad*4 + r;
            if (row < N_NODES) h2[(size_t)row*80 + col] = f2bb(acc[ct][r]);
        }
    }

    // fused att2: head0 = cols 0..39, head1 = cols 40..79.
    #pragma unroll
    for (int r = 0; r < 4; r++){
        float vs0 = 0.f, vs1 = 0.f, vd0 = 0.f, vd1 = 0.f;
        #pragma unroll
        for (int ct = 0; ct < 5; ct++){
            int col = ct*16 + l16;
            float ps = acc[ct][r]*asv[ct], pd = acc[ct][r]*adv[ct];
            if (col < 40){ vs0 += ps; vd0 += pd; } else { vs1 += ps; vd1 += pd; }
        }
        #pragma unroll
        for (int o = 1; o < 16; o <<= 1){
            vs0 += __shfl_xor(vs0, o, 64); vs1 += __shfl_xor(vs1, o, 64);
            vd0 += __shfl_xor(vd0, o, 64); vd1 += __shfl_xor(vd1, o, 64);
        }
        if (l16 == 0){
            int row = rowbase + quad*4 + r;
            if (row < N_NODES){
                aS[row*2 + 0] = vs0; aS[row*2 + 1] = vs1;
                aD[row*2 + 0] = vd0; aD[row*2 + 1] = vd1;
            }
        }
    }
}

// ---------------- layer-2 aggregation + fused head-mean/log_softmax ---------
__global__ __launch_bounds__(256) void k_agg2(
    const int* __restrict__ cur, const int* __restrict__ deg,
    const int* __restrict__ eidx, const uint32_t* __restrict__ wgt,
    const uint32_t* __restrict__ h2u, const void* __restrict__ b2v,
    const int* __restrict__ flag, void* __restrict__ out)
{
    int d = blockIdx.x*4 + (threadIdx.x >> 6);
    if (d >= N_NODES) return;
    int l = threadIdx.x & 63;
    if (l >= 40) return;                 // lane covers u32 l: feats 2l,2l+1; head = l>=20
    const int isb = *flag;
    int end = __builtin_amdgcn_readfirstlane(cur[d]);
    int j   = end - __builtin_amdgcn_readfirstlane(deg[d]);
    const int sh = (l >= 20) ? 16 : 0;
    float acc0 = 0.f, acc1 = 0.f;

#define P2(W, G) { float Wf = hcvt(W, sh); \
    acc0 += Wf * lo16(G); acc1 += Wf * hi16(G); }

    for (; j + 4 <= end; j += 4){
        int s0 = eidx[j], s1 = eidx[j+1], s2 = eidx[j+2], s3 = eidx[j+3];
        uint32_t w0 = wgt[j], w1 = wgt[j+1], w2 = wgt[j+2], w3 = wgt[j+3];
        uint32_t g0 = h2u[(size_t)s0*40 + l];
        uint32_t g1 = h2u[(size_t)s1*40 + l];
        uint32_t g2 = h2u[(size_t)s2*40 + l];
        uint32_t g3 = h2u[(size_t)s3*40 + l];
        P2(w0, g0); P2(w1, g1); P2(w2, g2); P2(w3, g3);
    }
    for (; j < end; j++){
        int s = eidx[j];
        uint32_t w = wgt[j];
        uint32_t g = h2u[(size_t)s*40 + l];
        P2(w, g);
    }
#undef P2

    // head-mean: lane l<20 combines its pair (head0) with lane l+20 (head1).
    float m0 = 0.5f*(acc0 + __shfl(acc0, l + 20, 64));
    float m1 = 0.5f*(acc1 + __shfl(acc1, l + 20, 64));
    float v0 = -1e30f, v1 = -1e30f;
    if (l < 20){
        v0 = m0 + rdf(b2v, 2*l,   isb);
        v1 = m1 + rdf(b2v, 2*l+1, isb);
    }
    // log_softmax over 40 classes held in lanes 0..19 (lanes 20..31 neutral).
    float mx = fmaxf(v0, v1);
    #pragma unroll
    for (int o = 1; o < 32; o <<= 1) mx = fmaxf(mx, __shfl_xor(mx, o, 64));
    float ex = (l < 20) ? __expf(v0 - mx) + __expf(v1 - mx) : 0.f;
    #pragma unroll
    for (int o = 1; o < 32; o <<= 1) ex += __shfl_xor(ex, o, 64);
    float lse = __logf(ex);
    if (l < 20){
        float r0 = v0 - mx - lse, r1 = v1 - mx - lse;
        if (isb){
            ((uint32_t*)out)[(size_t)d*20 + l] = pack2(r0, r1);
        } else {
            float2 wr; wr.x = r0; wr.y = r1;
            ((float2*)out)[(size_t)d*20 + l] = wr;
        }
    }
}

extern "C" void kernel_launch(void* const* d_in, const int* in_sizes, int n_in,
                              void* d_out, int out_size, void* d_ws, size_t ws_size,
                              hipStream_t stream)
{
    const void* x    = d_in[0];
    const int*  ei   = (const int*)d_in[1];
    const void* W1   = d_in[2];
    const void* as1  = d_in[3];
    const void* ad1  = d_in[4];
    // d_in[5] = b1: cancels exactly through BatchNorm mean subtraction
    const void* gamma = d_in[6];
    const void* beta  = d_in[7];
    const void* W2   = d_in[8];
    const void* as2  = d_in[9];
    const void* ad2  = d_in[10];
    const void* b2v  = d_in[11];
    const int* esrc = ei;
    const int* edst = ei + N_EDGES;

    // --- workspace: ~75 MB total (81.7 MB proven safe) ---
    char* ws = (char*)d_ws;
    size_t off = 0;
    auto alloc = [&](size_t bytes) {
        void* p = ws + off;
        off += (bytes + 255) & ~(size_t)255;
        return p;
    };
    int*   flag  = (int*)alloc(256);
    float* stats = (float*)alloc(sizeof(float)*256);
    int*   gcur  = (int*)alloc(sizeof(int)*NBUCK);
    float* aS1   = (float*)alloc(sizeof(float)*N_NODES*2);
    float* aD1   = (float*)alloc(sizeof(float)*N_NODES*2);
    float* aS2   = (float*)alloc(sizeof(float)*N_NODES*2);
    float* aD2   = (float*)alloc(sizeof(float)*N_NODES*2);
    int*   deg   = (int*)alloc(sizeof(int)*N_NODES);
    int*   cur   = (int*)alloc(sizeof(int)*N_NODES);
    uint32_t* staging = (uint32_t*)alloc(sizeof(uint32_t)*(size_t)NBUCK*BCAP); // 9.6 MB
    int*   eidx  = (int*)alloc(sizeof(int)*(size_t)NBUCK*BCAP);                // 9.6 MB
    unsigned short* h1  = (unsigned short*)alloc(2*(size_t)N_NODES*HID);  // 25.6 MB
    unsigned short* out1 = (unsigned short*)alloc(2*(size_t)N_NODES*HID); // 25.6 MB
    unsigned short* h2  = h1;            // alias: h1 dead after k_agg1
    uint32_t* wgt = staging;             // alias: staging dead after k_sort

    hipMemsetAsync(gcur, 0, sizeof(int)*NBUCK, stream);
    hipMemsetAsync(stats, 0, sizeof(float)*256, stream);

    k_detect<<<1, 256, 0, stream>>>((const uint32_t*)W1, flag);
    k_gemm1<<<3125, 256, 0, stream>>>(x, W1, as1, ad1, flag, h1, aS1, aD1);
    k_bin<<<NBB, 256, 0, stream>>>(esrc, edst, gcur, staging);
    k_sort<<<NBUCK, 256, 0, stream>>>(gcur, staging, deg, cur, eidx);
    k_ew<<<25000, 256, 0, stream>>>(cur, deg, eidx, aS1, aD1, wgt);
    k_agg1<<<25000, 256, 0, stream>>>(cur, deg, eidx, wgt,
                                      (const uint32_t*)h1, (uint32_t*)out1);
    k_bnstats<<<128, 256, 0, stream>>>((const uint32_t*)out1, stats);
    k_gemm2<<<1563, 256, 0, stream>>>(out1, stats, gamma, beta, W2, as2, ad2,
                                      flag, h2, aS2, aD2);
    k_ew<<<25000, 256, 0, stream>>>(cur, deg, eidx, aS2, aD2, wgt);
    k_agg2<<<25000, 256, 0, stream>>>(cur, deg, eidx, wgt,
                                      (const uint32_t*)h2, b2v, flag, d_out);
}

// Round 10
// 437.436 us; speedup vs baseline: 1.2136x; 1.0939x over previous
//
#include <hip/hip_runtime.h>
#include <hip/hip_bf16.h>
#include <hip/hip_fp16.h>
#include <stdint.h>

#define N_NODES 100000
#define N_EDGES 1600000
#define ET (N_EDGES + N_NODES)   // edges + self-loops
#define HID 128
#define C2 40
#define F2 80
#define NEG 0.2f
#define BN_EPS 1e-5f
#define NBUCK 391                // ceil(100000/256) coarse buckets (256 nodes each)
#define BCAP 6144                // slots per bucket (mean 4608, sd 66 -> +23 sigma)
#define NBB 640                  // bin-pass blocks
#define EPB ((ET + NBB - 1) / NBB)
#define CHK 512                  // per-wave LDS edge-weight cache (deg tail << 512)

typedef __hip_bfloat16 bf16;
typedef __attribute__((ext_vector_type(8))) short s8v;          // 8 bf16 MFMA A/B frag
typedef __attribute__((ext_vector_type(4))) float f4v;          // MFMA C/D frag
typedef __attribute__((ext_vector_type(4))) unsigned int u4v;
typedef __attribute__((ext_vector_type(2))) unsigned int u2v;

__device__ __forceinline__ float b2f(bf16 v){ return __bfloat162float(v); }
__device__ __forceinline__ float rdf(const void* p, size_t i, int isb){
    return isb ? b2f(((const bf16*)p)[i]) : ((const float*)p)[i];
}
__device__ __forceinline__ unsigned short f2bb(float v){
    bf16 h = __float2bfloat16(v);
    return *(unsigned short*)&h;
}
__device__ __forceinline__ uint32_t pack2(float a, float b){
    return (uint32_t)f2bb(a) | ((uint32_t)f2bb(b) << 16);
}
__device__ __forceinline__ uint32_t packh2(float a, float b){
    return (uint32_t)__half_as_ushort(__float2half(a))
         | ((uint32_t)__half_as_ushort(__float2half(b)) << 16);
}
__device__ __forceinline__ float lo16(uint32_t u){ return __uint_as_float(u << 16); }
__device__ __forceinline__ float hi16(uint32_t u){ return __uint_as_float(u & 0xFFFF0000u); }
__device__ __forceinline__ float hcvt(uint32_t w, int sh){
    return __half2float(__ushort_as_half((unsigned short)((w >> sh) & 0xFFFFu)));
}

// ---------------- init: dtype flag + zero gcur/stats ------------------------
__global__ __launch_bounds__(256) void k_init(
    const uint32_t* __restrict__ w1bits, int* __restrict__ flag,
    int* __restrict__ gcur, float* __restrict__ stats)
{
    __shared__ int cnt;
    int t = threadIdx.x;
    if (t == 0) cnt = 0;
    __syncthreads();
    uint32_t b = w1bits[t];
    float lo = __uint_as_float((b & 0xFFFFu) << 16);
    float a = fabsf(lo);
    if (a > 1e-8f && a < 1.0f) atomicAdd(&cnt, 1);
    for (int i = t; i < NBUCK; i += 256) gcur[i] = 0;
    stats[t] = 0.f;
    __syncthreads();
    if (t == 0) *flag = (cnt >= 192) ? 1 : 0;
}

// ---------------- GEMM1 (MFMA): h1 = x @ W1, + fused att1 dots --------------
__global__ __launch_bounds__(256) void k_gemm1(
    const void* __restrict__ x, const void* __restrict__ W1,
    const void* __restrict__ attS, const void* __restrict__ attD,
    const int* __restrict__ flag, unsigned short* __restrict__ h1,
    float* __restrict__ aS, float* __restrict__ aD)
{
    __shared__ __attribute__((aligned(16))) unsigned short wT[128*132]; // 33.8 KB
    const int isb = *flag;
    const int tid = threadIdx.x;
    if (isb) {
        const unsigned short* w = (const unsigned short*)W1;
        for (int idx = tid; idx < 128*128; idx += 256){
            int k = idx >> 7, n = idx & 127;
            wT[n*132 + k] = w[idx];
        }
    } else {
        const float* w = (const float*)W1;
        for (int idx = tid; idx < 128*128; idx += 256){
            int k = idx >> 7, n = idx & 127;
            wT[n*132 + k] = f2bb(w[idx]);
        }
    }
    __syncthreads();

    const int w4 = tid >> 6, lane = tid & 63, quad = lane >> 4, l16 = lane & 15;
    const int rowbase = blockIdx.x*32 + (w4 >> 1)*16;   // 3125*32 = 100000 exact
    const int colbase = (w4 & 1)*64;
    const int head = w4 & 1;

    s8v bfr[4][4];
    float asv[4], adv[4];
    #pragma unroll
    for (int ct = 0; ct < 4; ct++){
        int n = colbase + ct*16 + l16;
        asv[ct] = rdf(attS, n, isb);
        adv[ct] = rdf(attD, n, isb);
        #pragma unroll
        for (int s = 0; s < 4; s++){
            int k0 = s*32 + quad*8;
            const unsigned short* p = &wT[n*132 + k0];
            u2v a = *(const u2v*)p, b = *(const u2v*)(p+4);
            union { u4v u; s8v s; } cv; cv.u = (u4v){a[0],a[1],b[0],b[1]};
            bfr[ct][s] = cv.s;
        }
    }

    f4v acc[4];
    #pragma unroll
    for (int ct = 0; ct < 4; ct++) acc[ct] = (f4v){0.f,0.f,0.f,0.f};

    const int m = rowbase + l16;
    #pragma unroll
    for (int s = 0; s < 4; s++){
        int k0 = s*32 + quad*8;
        s8v af;
        if (isb){
            union { u4v u; s8v s; } cv;
            cv.u = *(const u4v*)((const unsigned short*)x + (size_t)m*128 + k0);
            af = cv.s;
        } else {
            const float* xp = (const float*)x + (size_t)m*128 + k0;
            f4v f0 = *(const f4v*)xp, f1 = *(const f4v*)(xp+4);
            union { u4v u; s8v s; } cv;
            cv.u = (u4v){pack2(f0[0],f0[1]), pack2(f0[2],f0[3]),
                         pack2(f1[0],f1[1]), pack2(f1[2],f1[3])};
            af = cv.s;
        }
        #pragma unroll
        for (int ct = 0; ct < 4; ct++)
            acc[ct] = __builtin_amdgcn_mfma_f32_16x16x32_bf16(af, bfr[ct][s], acc[ct], 0,0,0);
    }

    // C/D: col = lane&15, row = quad*4 + reg
    #pragma unroll
    for (int ct = 0; ct < 4; ct++){
        int col = colbase + ct*16 + l16;
        #pragma unroll
        for (int r = 0; r < 4; r++){
            int row = rowbase + quad*4 + r;
            h1[(size_t)row*128 + col] = f2bb(acc[ct][r]);
        }
    }

    // fused att1: per row, reduce acc*att over wave's 64 cols (one head).
    #pragma unroll
    for (int r = 0; r < 4; r++){
        float vs = 0.f, vd = 0.f;
        #pragma unroll
        for (int ct = 0; ct < 4; ct++){ vs += acc[ct][r]*asv[ct]; vd += acc[ct][r]*adv[ct]; }
        #pragma unroll
        for (int o = 1; o < 16; o <<= 1){
            vs += __shfl_xor(vs, o, 64);
            vd += __shfl_xor(vd, o, 64);
        }
        if (l16 == 0){
            int row = rowbase + quad*4 + r;
            aS[row*2 + head] = vs;
            aD[row*2 + head] = vd;
        }
    }
}

// ---------------- CSR pass 1: LDS-binned coarse scatter ---------------------
__global__ __launch_bounds__(256) void k_bin(
    const int* __restrict__ esrc, const int* __restrict__ edst,
    int* __restrict__ gcur, uint32_t* __restrict__ staging)
{
    __shared__ int cnt[NBUCK];
    __shared__ int bb[NBUCK];
    const int t = threadIdx.x;
    for (int i = t; i < NBUCK; i += 256) cnt[i] = 0;
    __syncthreads();
    const int e0 = blockIdx.x * EPB;
    const int e1 = (e0 + EPB < ET) ? e0 + EPB : ET;
    for (int e = e0 + t; e < e1; e += 256){
        int d = (e < N_EDGES) ? edst[e] : e - N_EDGES;
        atomicAdd(&cnt[d >> 8], 1);
    }
    __syncthreads();
    // rotate flush order by block to avoid lockstep per-address atomic chains
    const int bofs = (int)(blockIdx.x % NBUCK);
    for (int i = t; i < NBUCK; i += 256){
        int bkt = i + bofs; if (bkt >= NBUCK) bkt -= NBUCK;
        int c = cnt[bkt];
        bb[bkt] = c ? atomicAdd(&gcur[bkt], c) : 0;
        cnt[bkt] = 0;
    }
    __syncthreads();
    for (int e = e0 + t; e < e1; e += 256){
        int d, s;
        if (e < N_EDGES){ s = esrc[e]; d = edst[e]; } else { s = d = e - N_EDGES; }
        int b = d >> 8;
        int r = atomicAdd(&cnt[b], 1);
        int p = bb[b] + r;
        if (p < BCAP) staging[(size_t)b*BCAP + p] = ((uint32_t)s << 8) | (uint32_t)(d & 255);
    }
}

// ---------------- CSR pass 2: per-bucket fine counting sort -----------------
__global__ __launch_bounds__(256) void k_sort(
    const int* __restrict__ gcur, const uint32_t* __restrict__ staging,
    int* __restrict__ deg, int* __restrict__ cur, int* __restrict__ eidx)
{
    __shared__ int h[256], sc[256], rk[256];
    __shared__ int lsrc[BCAP];
    const int b = blockIdx.x;
    const int t = threadIdx.x;
    const int base = b * BCAP;
    int cnt = gcur[b];
    if (cnt > BCAP) cnt = BCAP;
    h[t] = 0; rk[t] = 0;
    __syncthreads();
    for (int i = t; i < cnt; i += 256)
        atomicAdd(&h[staging[base + i] & 255u], 1);
    __syncthreads();
    sc[t] = h[t];
    __syncthreads();
    for (int off = 1; off < 256; off <<= 1){
        int v = (t >= off) ? sc[t - off] : 0;
        __syncthreads();
        sc[t] += v;
        __syncthreads();
    }
    int dg = b*256 + t;
    if (dg < N_NODES){
        deg[dg] = h[t];
        cur[dg] = base + sc[t];    // end pointer; start = end - deg
    }
    __syncthreads();
    for (int i = t; i < cnt; i += 256){
        uint32_t w = staging[base + i];
        int dl = w & 255u;
        int r = atomicAdd(&rk[dl], 1);
        lsrc[sc[dl] - h[dl] + r] = (int)(w >> 8);
    }
    __syncthreads();
    for (int i = t; i < cnt; i += 256) eidx[base + i] = lsrc[i];
}

// ---------------- layer-1 agg, fused softmax weights (wave-private LDS) -----
__global__ __launch_bounds__(256) void k_agg1(
    const int* __restrict__ cur, const int* __restrict__ deg,
    const int* __restrict__ eidx, const float* __restrict__ aS,
    const float* __restrict__ aD, const uint32_t* __restrict__ h1u,
    uint32_t* __restrict__ out1u)
{
    __shared__ uint2 lse[4][CHK];        // 16 KB: (src, half2(e0,e1)) per edge
    const int wv = threadIdx.x >> 6;
    int d = blockIdx.x*4 + wv;
    if (d >= N_NODES) return;
    const int l = threadIdx.x & 63;      // lane: feats 2l,2l+1; head = l>=32
    int end   = __builtin_amdgcn_readfirstlane(cur[d]);
    int start = end - __builtin_amdgcn_readfirstlane(deg[d]);
    float2 ad = *(const float2*)(aD + d*2);
    const int sh = (l >= 32) ? 16 : 0;
    float den0 = 0.f, den1 = 0.f, acc0 = 0.f, acc1 = 0.f;

#define P1(P) { float Wf = hcvt((P).y, sh); uint32_t G = h1u[(size_t)(P).x*64 + l]; \
    acc0 += Wf * lo16(G); acc1 += Wf * hi16(G); }

    for (int c0 = start; c0 < end; c0 += CHK){
        int c1 = (c0 + CHK < end) ? c0 + CHK : end;
        int n = c1 - c0;
        // phase 1: lanes parallel over edges — exp once, cache in LDS
        for (int j = c0 + l; j < c1; j += 64){
            int s = eidx[j];
            float2 as = *(const float2*)(aS + s*2);
            float al0 = as.x + ad.x, al1 = as.y + ad.y;
            al0 = al0 > 0.f ? al0 : NEG*al0;
            al1 = al1 > 0.f ? al1 : NEG*al1;
            float e0 = __expf(al0), e1 = __expf(al1);
            lse[wv][j - c0] = make_uint2((uint32_t)s, packh2(e0, e1));
            den0 += e0; den1 += e1;
        }
        // same-wave LDS RAW: in-order per wave, no block barrier needed
        int i = 0;
        for (; i + 4 <= n; i += 4){
            uint2 p0 = lse[wv][i],   p1 = lse[wv][i+1];
            uint2 p2 = lse[wv][i+2], p3 = lse[wv][i+3];
            P1(p0); P1(p1); P1(p2); P1(p3);
        }
        for (; i < n; i++){ uint2 p = lse[wv][i]; P1(p); }
    }
#undef P1
    #pragma unroll
    for (int o = 1; o < 64; o <<= 1){
        den0 += __shfl_xor(den0, o, 64);
        den1 += __shfl_xor(den1, o, 64);
    }
    float r = 1.f / fmaxf((l < 32) ? den0 : den1, 1e-20f);
    out1u[(size_t)d*64 + l] = pack2(acc0*r, acc1*r);
}

// ---------------- BatchNorm stats: per-block LDS reduce, then 1 atomic ------
__global__ __launch_bounds__(256) void k_bnstats(
    const uint32_t* __restrict__ out1u, float* __restrict__ stats)
{
    __shared__ float red[4][64][4];      // wave x feat-pair x {s0,s1,q0,q1} = 4 KB
    int fp = threadIdx.x & 63;
    int wv = threadIdx.x >> 6;
    float s0 = 0.f, q0 = 0.f, s1 = 0.f, q1 = 0.f;
    for (int r = blockIdx.x*4 + wv; r < N_NODES; r += 512){
        uint32_t u = out1u[(size_t)r*64 + fp];
        float f0 = lo16(u), f1 = hi16(u);
        s0 += f0; q0 += f0*f0; s1 += f1; q1 += f1*f1;
    }
    red[wv][fp][0] = s0; red[wv][fp][1] = s1;
    red[wv][fp][2] = q0; red[wv][fp][3] = q1;
    __syncthreads();
    if (threadIdx.x < 64){
        int l = threadIdx.x;
        float a0=0.f, a1=0.f, b0=0.f, b1=0.f;
        #pragma unroll
        for (int w = 0; w < 4; w++){
            a0 += red[w][l][0]; a1 += red[w][l][1];
            b0 += red[w][l][2]; b1 += red[w][l][3];
        }
        unsafeAtomicAdd(&stats[2*l],       a0);
        unsafeAtomicAdd(&stats[2*l+1],     a1);
        unsafeAtomicAdd(&stats[128+2*l],   b0);
        unsafeAtomicAdd(&stats[128+2*l+1], b1);
    }
}

// ---------------- GEMM2 (MFMA): h2 = BN(out1) @ W2, + fused att2, BN-fin ----
__global__ __launch_bounds__(256) void k_gemm2(
    const unsigned short* __restrict__ out1b, const float* __restrict__ stats,
    const void* __restrict__ gamma, const void* __restrict__ beta,
    const void* __restrict__ W2, const void* __restrict__ attS,
    const void* __restrict__ attD, const int* __restrict__ flag,
    unsigned short* __restrict__ h2, float* __restrict__ aS, float* __restrict__ aD)
{
    __shared__ __attribute__((aligned(16))) unsigned short wT[80*132]; // 21.1 KB
    __shared__ float scl[128], shl[128];
    const int isb = *flag;
    const int tid = threadIdx.x;
    for (int idx = tid; idx < 128*80; idx += 256){
        int k = idx / 80, n = idx - k*80;
        wT[n*132 + k] = isb ? ((const unsigned short*)W2)[idx]
                            : f2bb(((const float*)W2)[idx]);
    }
    if (tid < 128){   // inline BN finalize
        float mean = stats[tid] * (1.f / N_NODES);
        float var = fmaxf(stats[128+tid] * (1.f / N_NODES) - mean*mean, 0.f);
        float rs = rsqrtf(var + BN_EPS);
        float sc = rdf(gamma, tid, isb) * rs;
        scl[tid] = sc;
        shl[tid] = rdf(beta, tid, isb) - mean*sc;
    }
    __syncthreads();

    const int w4 = tid >> 6, lane = tid & 63, quad = lane >> 4, l16 = lane & 15;
    const int rowbase = blockIdx.x*64 + w4*16;

    s8v bfr[5][4];
    float asv[5], adv[5];
    #pragma unroll
    for (int ct = 0; ct < 5; ct++){
        int n = ct*16 + l16;
        asv[ct] = rdf(attS, n, isb);
        adv[ct] = rdf(attD, n, isb);
        #pragma unroll
        for (int s = 0; s < 4; s++){
            int k0 = s*32 + quad*8;
            const unsigned short* p = &wT[n*132 + k0];
            u2v a = *(const u2v*)p, b = *(const u2v*)(p+4);
            union { u4v u; s8v s; } cv; cv.u = (u4v){a[0],a[1],b[0],b[1]};
            bfr[ct][s] = cv.s;
        }
    }

    f4v acc[5];
    #pragma unroll
    for (int ct = 0; ct < 5; ct++) acc[ct] = (f4v){0.f,0.f,0.f,0.f};

    int m = rowbase + l16;
    int mc = m < N_NODES ? m : N_NODES - 1;
    #pragma unroll
    for (int s = 0; s < 4; s++){
        int k0 = s*32 + quad*8;
        union { u4v u; s8v s8; } cin;
        cin.u = *(const u4v*)(out1b + (size_t)mc*128 + k0);
        u4v up;
        #pragma unroll
        for (int i = 0; i < 4; i++){
            float f0 = lo16(cin.u[i]), f1 = hi16(cin.u[i]);
            int k = k0 + 2*i;
            up[i] = pack2(f0*scl[k] + shl[k], f1*scl[k+1] + shl[k+1]);
        }
        union { u4v u; s8v s8; } cv; cv.u = up;
        #pragma unroll
        for (int ct = 0; ct < 5; ct++)
            acc[ct] = __builtin_amdgcn_mfma_f32_16x16x32_bf16(cv.s8, bfr[ct][s], acc[ct], 0,0,0);
    }

    #pragma unroll
    for (int ct = 0; ct < 5; ct++){
        int col = ct*16 + l16;
        #pragma unroll
        for (int r = 0; r < 4; r++){
            int row = rowbase + quad*4 + r;
            if (row < N_NODES) h2[(size_t)row*80 + col] = f2bb(acc[ct][r]);
        }
    }

    // fused att2: head0 = cols 0..39, head1 = cols 40..79.
    #pragma unroll
    for (int r = 0; r < 4; r++){
        float vs0 = 0.f, vs1 = 0.f, vd0 = 0.f, vd1 = 0.f;
        #pragma unroll
        for (int ct = 0; ct < 5; ct++){
            int col = ct*16 + l16;
            float ps = acc[ct][r]*asv[ct], pd = acc[ct][r]*adv[ct];
            if (col < 40){ vs0 += ps; vd0 += pd; } else { vs1 += ps; vd1 += pd; }
        }
        #pragma unroll
        for (int o = 1; o < 16; o <<= 1){
            vs0 += __shfl_xor(vs0, o, 64); vs1 += __shfl_xor(vs1, o, 64);
            vd0 += __shfl_xor(vd0, o, 64); vd1 += __shfl_xor(vd1, o, 64);
        }
        if (l16 == 0){
            int row = rowbase + quad*4 + r;
            if (row < N_NODES){
                aS[row*2 + 0] = vs0; aS[row*2 + 1] = vs1;
                aD[row*2 + 0] = vd0; aD[row*2 + 1] = vd1;
            }
        }
    }
}

// ---------------- layer-2 agg, fused weights + head-mean/log_softmax --------
__global__ __launch_bounds__(256) void k_agg2(
    const int* __restrict__ cur, const int* __restrict__ deg,
    const int* __restrict__ eidx, const float* __restrict__ aS,
    const float* __restrict__ aD, const uint32_t* __restrict__ h2u,
    const void* __restrict__ b2v, const int* __restrict__ flag,
    void* __restrict__ out)
{
    __shared__ uint2 lse[4][CHK];        // 16 KB
    const int wv = threadIdx.x >> 6;
    int d = blockIdx.x*4 + wv;
    if (d >= N_NODES) return;
    const int l = threadIdx.x & 63;      // l<40: u32 l -> feats 2l,2l+1; head = l>=20
    const int isb = *flag;
    int end   = __builtin_amdgcn_readfirstlane(cur[d]);
    int start = end - __builtin_amdgcn_readfirstlane(deg[d]);
    float2 ad = *(const float2*)(aD + d*2);
    const int sh = (l >= 20) ? 16 : 0;
    const bool act = l < 40;
    float den0 = 0.f, den1 = 0.f, acc0 = 0.f, acc1 = 0.f;

#define P2(P) { float Wf = hcvt((P).y, sh); \
    uint32_t G = act ? h2u[(size_t)(P).x*40 + l] : 0u; \
    acc0 += Wf * lo16(G); acc1 += Wf * hi16(G); }

    for (int c0 = start; c0 < end; c0 += CHK){
        int c1 = (c0 + CHK < end) ? c0 + CHK : end;
        int n = c1 - c0;
        for (int j = c0 + l; j < c1; j += 64){
            int s = eidx[j];
            float2 as = *(const float2*)(aS + s*2);
            float al0 = as.x + ad.x, al1 = as.y + ad.y;
            al0 = al0 > 0.f ? al0 : NEG*al0;
            al1 = al1 > 0.f ? al1 : NEG*al1;
            float e0 = __expf(al0), e1 = __expf(al1);
            lse[wv][j - c0] = make_uint2((uint32_t)s, packh2(e0, e1));
            den0 += e0; den1 += e1;
        }
        int i = 0;
        for (; i + 4 <= n; i += 4){
            uint2 p0 = lse[wv][i],   p1 = lse[wv][i+1];
            uint2 p2 = lse[wv][i+2], p3 = lse[wv][i+3];
            P2(p0); P2(p1); P2(p2); P2(p3);
        }
        for (; i < n; i++){ uint2 p = lse[wv][i]; P2(p); }
    }
#undef P2
    #pragma unroll
    for (int o = 1; o < 64; o <<= 1){
        den0 += __shfl_xor(den0, o, 64);
        den1 += __shfl_xor(den1, o, 64);
    }
    float r = 1.f / fmaxf((l < 20) ? den0 : den1, 1e-20f);
    acc0 *= r; acc1 *= r;

    // head-mean: lane l<20 combines its pair (head0) with lane l+20 (head1).
    float m0 = 0.5f*(acc0 + __shfl(acc0, l + 20, 64));
    float m1 = 0.5f*(acc1 + __shfl(acc1, l + 20, 64));
    float v0 = -1e30f, v1 = -1e30f;
    if (l < 20){
        v0 = m0 + rdf(b2v, 2*l,   isb);
        v1 = m1 + rdf(b2v, 2*l+1, isb);
    }
    // log_softmax over 40 classes held in lanes 0..19 (lanes 20..31 neutral).
    float mx = fmaxf(v0, v1);
    #pragma unroll
    for (int o = 1; o < 32; o <<= 1) mx = fmaxf(mx, __shfl_xor(mx, o, 64));
    float ex = (l < 20) ? __expf(v0 - mx) + __expf(v1 - mx) : 0.f;
    #pragma unroll
    for (int o = 1; o < 32; o <<= 1) ex += __shfl_xor(ex, o, 64);
    float lse2 = __logf(ex);
    if (l < 20){
        float r0 = v0 - mx - lse2, r1 = v1 - mx - lse2;
        if (isb){
            ((uint32_t*)out)[(size_t)d*20 + l] = pack2(r0, r1);
        } else {
            float2 wr; wr.x = r0; wr.y = r1;
            ((float2*)out)[(size_t)d*20 + l] = wr;
        }
    }
}

extern "C" void kernel_launch(void* const* d_in, const int* in_sizes, int n_in,
                              void* d_out, int out_size, void* d_ws, size_t ws_size,
                              hipStream_t stream)
{
    const void* x    = d_in[0];
    const int*  ei   = (const int*)d_in[1];
    const void* W1   = d_in[2];
    const void* as1  = d_in[3];
    const void* ad1  = d_in[4];
    // d_in[5] = b1: cancels exactly through BatchNorm mean subtraction
    const void* gamma = d_in[6];
    const void* beta  = d_in[7];
    const void* W2   = d_in[8];
    const void* as2  = d_in[9];
    const void* ad2  = d_in[10];
    const void* b2v  = d_in[11];
    const int* esrc = ei;
    const int* edst = ei + N_EDGES;

    // --- workspace: ~75 MB total (81.7 MB proven safe) ---
    char* ws = (char*)d_ws;
    size_t off = 0;
    auto alloc = [&](size_t bytes) {
        void* p = ws + off;
        off += (bytes + 255) & ~(size_t)255;
        return p;
    };
    int*   flag  = (int*)alloc(256);
    float* stats = (float*)alloc(sizeof(float)*256);
    int*   gcur  = (int*)alloc(sizeof(int)*NBUCK);
    float* aS1   = (float*)alloc(sizeof(float)*N_NODES*2);
    float* aD1   = (float*)alloc(sizeof(float)*N_NODES*2);
    float* aS2   = (float*)alloc(sizeof(float)*N_NODES*2);
    float* aD2   = (float*)alloc(sizeof(float)*N_NODES*2);
    int*   deg   = (int*)alloc(sizeof(int)*N_NODES);
    int*   cur   = (int*)alloc(sizeof(int)*N_NODES);
    uint32_t* staging = (uint32_t*)alloc(sizeof(uint32_t)*(size_t)NBUCK*BCAP); // 9.6 MB
    int*   eidx  = (int*)alloc(sizeof(int)*(size_t)NBUCK*BCAP);                // 9.6 MB
    unsigned short* h1  = (unsigned short*)alloc(2*(size_t)N_NODES*HID);  // 25.6 MB
    unsigned short* out1 = (unsigned short*)alloc(2*(size_t)N_NODES*HID); // 25.6 MB
    unsigned short* h2  = h1;            // alias: h1 dead after k_agg1

    k_init<<<1, 256, 0, stream>>>((const uint32_t*)W1, flag, gcur, stats);
    k_gemm1<<<3125, 256, 0, stream>>>(x, W1, as1, ad1, flag, h1, aS1, aD1);
    k_bin<<<NBB, 256, 0, stream>>>(esrc, edst, gcur, staging);
    k_sort<<<NBUCK, 256, 0, stream>>>(gcur, staging, deg, cur, eidx);
    k_agg1<<<25000, 256, 0, stream>>>(cur, deg, eidx, aS1, aD1,
                                      (const uint32_t*)h1, (uint32_t*)out1);
    k_bnstats<<<128, 256, 0, stream>>>((const uint32_t*)out1, stats);
    k_gemm2<<<1563, 256, 0, stream>>>(out1, stats, gamma, beta, W2, as2, ad2,
                                      flag, h2, aS2, aD2);
    k_agg2<<<25000, 256, 0, stream>>>(cur, deg, eidx, aS2, aD2,
                                      (const uint32_t*)h2, b2v, flag, d_out);
}